// Round 9
// baseline (4770.371 us; speedup 1.0000x reference)
//
#include <hip/hip_runtime.h>
#include <hip/hip_bf16.h>

// GCN 2-layer: relu(A_hat @ relu(A_hat @ X @ W1 + b1) @ W2 + b2)
//   L1: aggregate X (256f) -> split-bf16; MFMA GEMM W1 (+b1, relu) -> split-bf16 H
//   L2: MFMA GEMM W2 (epilogue: *dinv) -> fp32 Ys; aggregate Ys (250f) + b2 + relu
//   GEMMs: bf16 MFMA hi/lo split (3 products), ~2^-16 rel error.
//   Aggregation: dest-chunk blocks (25 nodes) w/ LDS fp32 accumulators; edges
//   counting-sorted by (chunk, src>>7) so resident blocks sweep sources in
//   near-lockstep -> gathers hit an L2-resident band (r7: FETCH was 15x compulsory).

#define F_IN  256
#define F_HID 512
#define F_OUT 250
#define AGG_CHUNK 25
#define ACC_STR   257   // acc row stride (floats): bank=(ld+lane)%32 -> 2-way, free

using bf16x8 = __attribute__((ext_vector_type(8))) short;
using f32x4  = __attribute__((ext_vector_type(4))) float;

__device__ __forceinline__ ushort f32_bf16_rne(float f) {
    uint u = __float_as_uint(f);
    u += 0x7FFFu + ((u >> 16) & 1u);
    return (ushort)(u >> 16);
}
__device__ __forceinline__ float bf16u_f32(ushort h) {
    return __uint_as_float(((uint)h) << 16);
}

// ---------------- degree + dinv ----------------

__global__ __launch_bounds__(256) void hist_kernel(const int* __restrict__ col, int* cnt, int E) {
    int e = blockIdx.x * 256 + threadIdx.x;
    if (e < E) atomicAdd(&cnt[col[e]], 1);
}

__global__ __launch_bounds__(256) void dinv_kernel(const int* __restrict__ cnt, float* dinv, int n) {
    int i = blockIdx.x * 256 + threadIdx.x;
    if (i < n) dinv[i] = rsqrtf((float)(cnt[i] + 1));  // +1 self loop
}

// ---------------- key histogram into keyptr (scanned in-place later) ------------
// key = (col/CHUNK)*NW + (row>>7)

__global__ __launch_bounds__(256) void keyhist_kernel(const int* __restrict__ row, const int* __restrict__ col,
                                                      int* keyptr, int E, int NW) {
    int e = blockIdx.x * 256 + threadIdx.x;
    if (e < E) {
        int key = (col[e] / AGG_CHUNK) * NW + (row[e] >> 7);
        atomicAdd(&keyptr[key], 1);
    }
}

// ---------------- multi-block exclusive scan, in place (A/B/C) ----------------

__global__ __launch_bounds__(1024) void scanA_kernel(int* ptr, int* partial, int K) {
    __shared__ int wsum[16];
    int t = threadIdx.x;
    int i = blockIdx.x * 1024 + t;
    int lane = t & 63, wid = t >> 6;
    int v = (i < K) ? ptr[i] : 0;
    int s = v;
    #pragma unroll
    for (int off = 1; off < 64; off <<= 1) {
        int u = __shfl_up(s, off, 64);
        if (lane >= off) s += u;
    }
    if (lane == 63) wsum[wid] = s;
    __syncthreads();
    if (wid == 0 && lane < 16) {
        int ws = wsum[lane];
        #pragma unroll
        for (int off = 1; off < 16; off <<= 1) {
            int u = __shfl_up(ws, off, 64);
            if (lane >= off) ws += u;
        }
        wsum[lane] = ws;
    }
    __syncthreads();
    int wbase = (wid == 0) ? 0 : wsum[wid - 1];
    int incl = wbase + s;
    if (i < K) ptr[i] = incl - v;               // block-local exclusive
    if (t == 1023) partial[blockIdx.x] = incl;  // block total
}

__global__ __launch_bounds__(1024) void scanB_kernel(int* partial, int nb) {
    __shared__ int wsum[16];
    int t = threadIdx.x;
    int lane = t & 63, wid = t >> 6;
    int v = (t < nb) ? partial[t] : 0;
    int s = v;
    #pragma unroll
    for (int off = 1; off < 64; off <<= 1) {
        int u = __shfl_up(s, off, 64);
        if (lane >= off) s += u;
    }
    if (lane == 63) wsum[wid] = s;
    __syncthreads();
    if (wid == 0 && lane < 16) {
        int ws = wsum[lane];
        #pragma unroll
        for (int off = 1; off < 16; off <<= 1) {
            int u = __shfl_up(ws, off, 64);
            if (lane >= off) ws += u;
        }
        wsum[lane] = ws;
    }
    __syncthreads();
    int wbase = (wid == 0) ? 0 : wsum[wid - 1];
    if (t < nb) partial[t] = wbase + s - v;  // exclusive
}

__global__ __launch_bounds__(1024) void scanC_kernel(int* ptr, const int* __restrict__ partial,
                                                     int K, int E) {
    int i = blockIdx.x * 1024 + threadIdx.x;
    if (i < K) ptr[i] += partial[blockIdx.x];
    if (i == 0) ptr[K] = E;
}

// ---------------- fill sorted edge records ----------------
// csrd[pos] = { (row<<7)|ldest, bits(dinv[row]) }, pos sorted by (chunk, src>>7)

__global__ __launch_bounds__(256) void fillkey_kernel(const int* __restrict__ row, const int* __restrict__ col,
                                                      const int* __restrict__ keyptr, int* keycur,
                                                      const float* __restrict__ dinv,
                                                      int2* __restrict__ csrd, int E, int NW) {
    int e = blockIdx.x * 256 + threadIdx.x;
    if (e < E) {
        int r = row[e], c = col[e];
        int chunk = c / AGG_CHUNK;
        int key = chunk * NW + (r >> 7);
        int pos = keyptr[key] + atomicAdd(&keycur[key], 1);
        csrd[pos] = make_int2((r << 7) | (c - chunk * AGG_CHUNK), __float_as_int(dinv[r]));
    }
}

// ---------------- W transpose + split:  W[K][N] fp32 -> WT_hi/lo [N][K] bf16 ----------------

__global__ __launch_bounds__(256) void wsplit_kernel(const float* __restrict__ W,
                                                     ushort* __restrict__ WThi, ushort* __restrict__ WTlo,
                                                     int K, int N) {
    __shared__ float tile[32][33];
    int t = threadIdx.x;
    int k0 = blockIdx.x * 32, n0 = blockIdx.y * 32;
    int r = t >> 3, c = (t & 7) * 4;
    #pragma unroll
    for (int q = 0; q < 4; ++q) {
        float z = 0.f;
        if (n0 + c + q < N) z = W[(size_t)(k0 + r) * N + n0 + c + q];
        tile[r][c + q] = z;
    }
    __syncthreads();
    int nr = t >> 3, kq = (t & 7) * 4;
    int gn = n0 + nr;
    if (gn < N) {
        ushort4 h4, l4;
        ushort* hp = &h4.x; ushort* lp = &l4.x;
        #pragma unroll
        for (int q = 0; q < 4; ++q) {
            float z = tile[kq + q][nr];
            ushort h = f32_bf16_rne(z);
            hp[q] = h;
            lp[q] = f32_bf16_rne(z - bf16u_f32(h));
        }
        *(ushort4*)&WThi[(size_t)gn * K + k0 + kq] = h4;
        *(ushort4*)&WTlo[(size_t)gn * K + k0 + kq] = l4;
    }
}

// ---------------- aggregation: dest-chunk LDS accumulators, src-sweep edges ------
// MODE 1: out = split-bf16 of dinv[c]*acc; acc init = dinv[c]*X[c]; edges add dr*X[r]
// MODE 2: out = relu(dinv[c]*acc + bias) fp32 [n][250]; X rows prescaled by dinv

template<int MODE>
__global__ __launch_bounds__(512) void agg_lds(const float* __restrict__ X,
                                               const float* __restrict__ dinv,
                                               const int* __restrict__ keyptr,
                                               const int2* __restrict__ csrd,
                                               const float* __restrict__ bias,
                                               float* __restrict__ out,
                                               ushort* __restrict__ outHi, ushort* __restrict__ outLo,
                                               int n, int NW) {
    __shared__ float acc[AGG_CHUNK * ACC_STR];
    int b = blockIdx.x;
    int t = threadIdx.x;
    int lane = t & 63, wid = t >> 6;
    int c0 = b * AGG_CHUNK;

    // init: self-loop term
    for (int idx = t; idx < AGG_CHUNK * 256; idx += 512) {
        int ld = idx >> 8, f = idx & 255;
        int c = c0 + ld;
        float z = 0.f;
        if (c < n) {
            z = X[(size_t)c * 256 + f];
            if (MODE == 1) z *= dinv[c];
        }
        acc[ld * ACC_STR + f] = z;
    }
    __syncthreads();

    int e0 = keyptr[b * NW], e1 = keyptr[(b + 1) * NW];
    for (int e = e0 + wid * 8; e < e1; e += 64) {
        int m = e1 - e;  // >= 1
        int2 rec[8];
        #pragma unroll
        for (int q = 0; q < 8; ++q)
            rec[q] = (q < m) ? csrd[e + q] : make_int2(-1, 0);
        float v0[8], v1[8], v2[8], v3[8];
        #pragma unroll
        for (int q = 0; q < 8; ++q) {
            if (rec[q].x >= 0) {
                const float* xp = X + (size_t)(rec[q].x >> 7) * 256 + lane;
                v0[q] = xp[0]; v1[q] = xp[64]; v2[q] = xp[128]; v3[q] = xp[192];
            }
        }
        #pragma unroll
        for (int q = 0; q < 8; ++q) {
            if (rec[q].x >= 0) {
                float* ap = acc + (rec[q].x & 127) * ACC_STR + lane;
                if (MODE == 1) {
                    float dr = __int_as_float(rec[q].y);
                    atomicAdd(ap,       dr * v0[q]);
                    atomicAdd(ap + 64,  dr * v1[q]);
                    atomicAdd(ap + 128, dr * v2[q]);
                    atomicAdd(ap + 192, dr * v3[q]);
                } else {
                    atomicAdd(ap,       v0[q]);
                    atomicAdd(ap + 64,  v1[q]);
                    atomicAdd(ap + 128, v2[q]);
                    atomicAdd(ap + 192, v3[q]);
                }
            }
        }
    }
    __syncthreads();

    // writeout
    if (MODE == 1) {
        for (int idx = t; idx < AGG_CHUNK * 256; idx += 512) {
            int ld = idx >> 8, f = idx & 255;
            int c = c0 + ld;
            if (c >= n) continue;
            float z = acc[ld * ACC_STR + f] * dinv[c];
            ushort h = f32_bf16_rne(z);
            outHi[(size_t)c * 256 + f] = h;
            outLo[(size_t)c * 256 + f] = f32_bf16_rne(z - bf16u_f32(h));
        }
    } else {
        for (int idx = t; idx < AGG_CHUNK * 256; idx += 512) {
            int ld = idx >> 8, f = idx & 255;
            if (f >= F_OUT) continue;
            int c = c0 + ld;
            if (c >= n) continue;
            float z = fmaxf(acc[ld * ACC_STR + f] * dinv[c] + bias[f], 0.f);
            out[(size_t)c * F_OUT + f] = z;
        }
    }
}

// ---------------- MFMA split-bf16 GEMM ----------------
// C[M,N] = (Ahi+Alo)[M,K] @ (Bhi+Blo)^T-stored[N,K]   (3-product split)
// BM=BN=128, BK=32, 256 thr (4 waves, 2x2), per-wave 64x64 = 4x4 frags of 16x16x32.
// SPLIT_OUT: +bias, relu, emit split-bf16 (ld=N). else: fp32 out *dinv[row], ldc param.

template<bool SPLIT_OUT>
__global__ __launch_bounds__(256) void gemm_mfma(const ushort* __restrict__ Ahi, const ushort* __restrict__ Alo,
                                                 const ushort* __restrict__ Bhi, const ushort* __restrict__ Blo,
                                                 const float* __restrict__ bias,
                                                 const float* __restrict__ dinv,
                                                 float* __restrict__ Cf,
                                                 ushort* __restrict__ Chi, ushort* __restrict__ Clo,
                                                 int M, int N, int K, int ldc) {
    __shared__ ushort As_hi[128][40];   // 80B rows: 16B-aligned, <=2-way bank alias
    __shared__ ushort As_lo[128][40];
    __shared__ ushort Bs_hi[128][40];
    __shared__ ushort Bs_lo[128][40];

    int t = threadIdx.x;
    int row0 = blockIdx.x * 128;
    int col0 = blockIdx.y * 128;
    int lane = t & 63;
    int w = t >> 6;
    int wr = w >> 1, wc = w & 1;       // wave 64x64 sub-tile
    int lr = lane & 15, lg = lane >> 4;

    int srow = t >> 2;                 // staging: 64 rows per pass
    int soct = (t & 3) * 8;            // k-octet within BK=32

    f32x4 acc[4][4];
    #pragma unroll
    for (int i = 0; i < 4; ++i)
        #pragma unroll
        for (int j = 0; j < 4; ++j)
            acc[i][j] = (f32x4){0.f, 0.f, 0.f, 0.f};

    for (int k0 = 0; k0 < K; k0 += 32) {
        #pragma unroll
        for (int h = 0; h < 2; ++h) {
            int r = srow + h * 64;
            int4 zero = make_int4(0, 0, 0, 0);
            int ga = row0 + r;
            int4 vh = zero, vl = zero;
            if (ga < M) {
                vh = *(const int4*)(Ahi + (size_t)ga * K + k0 + soct);
                vl = *(const int4*)(Alo + (size_t)ga * K + k0 + soct);
            }
            *(int4*)&As_hi[r][soct] = vh;
            *(int4*)&As_lo[r][soct] = vl;
            int gb = col0 + r;
            int4 wh = zero, wl = zero;
            if (gb < N) {
                wh = *(const int4*)(Bhi + (size_t)gb * K + k0 + soct);
                wl = *(const int4*)(Blo + (size_t)gb * K + k0 + soct);
            }
            *(int4*)&Bs_hi[r][soct] = wh;
            *(int4*)&Bs_lo[r][soct] = wl;
        }
        __syncthreads();

        bf16x8 ah[4], al[4], bh[4], bl[4];
        #pragma unroll
        for (int mi = 0; mi < 4; ++mi) {
            ah[mi] = *(const bf16x8*)&As_hi[wr * 64 + mi * 16 + lr][lg * 8];
            al[mi] = *(const bf16x8*)&As_lo[wr * 64 + mi * 16 + lr][lg * 8];
        }
        #pragma unroll
        for (int ni = 0; ni < 4; ++ni) {
            bh[ni] = *(const bf16x8*)&Bs_hi[wc * 64 + ni * 16 + lr][lg * 8];
            bl[ni] = *(const bf16x8*)&Bs_lo[wc * 64 + ni * 16 + lr][lg * 8];
        }
        #pragma unroll
        for (int mi = 0; mi < 4; ++mi)
            #pragma unroll
            for (int ni = 0; ni < 4; ++ni) {
                acc[mi][ni] = __builtin_amdgcn_mfma_f32_16x16x32_bf16(ah[mi], bh[ni], acc[mi][ni], 0, 0, 0);
                acc[mi][ni] = __builtin_amdgcn_mfma_f32_16x16x32_bf16(ah[mi], bl[ni], acc[mi][ni], 0, 0, 0);
                acc[mi][ni] = __builtin_amdgcn_mfma_f32_16x16x32_bf16(al[mi], bh[ni], acc[mi][ni], 0, 0, 0);
            }
        __syncthreads();
    }

    // epilogue: D lane map (verified): row=(lane>>4)*4+reg, col=lane&15
    #pragma unroll
    for (int mi = 0; mi < 4; ++mi) {
        int rbase = row0 + wr * 64 + mi * 16 + lg * 4;
        #pragma unroll
        for (int ni = 0; ni < 4; ++ni) {
            int cg = col0 + wc * 64 + ni * 16 + lr;
            f32x4 a = acc[mi][ni];
            if (SPLIT_OUT) {
                float bia = bias[cg];
                #pragma unroll
                for (int r = 0; r < 4; ++r) {
                    int rg = rbase + r;
                    if (rg < M) {
                        float z = fmaxf(a[r] + bia, 0.f);
                        ushort h = f32_bf16_rne(z);
                        Chi[(size_t)rg * N + cg] = h;
                        Clo[(size_t)rg * N + cg] = f32_bf16_rne(z - bf16u_f32(h));
                    }
                }
            } else {
                if (cg < N) {
                    #pragma unroll
                    for (int r = 0; r < 4; ++r) {
                        int rg = rbase + r;
                        if (rg < M) Cf[(size_t)rg * ldc + cg] = a[r] * dinv[rg];  // fold A_hat's dinv
                    }
                }
            }
        }
    }
}

// ---------------- launch ----------------

extern "C" void kernel_launch(void* const* d_in, const int* in_sizes, int n_in,
                              void* d_out, int out_size, void* d_ws, size_t ws_size,
                              hipStream_t stream) {
    const float* x   = (const float*)d_in[0];
    const int*   ei  = (const int*)d_in[1];
    const float* W1  = (const float*)d_in[2];
    const float* b1  = (const float*)d_in[3];
    const float* W2  = (const float*)d_in[4];
    const float* b2  = (const float*)d_in[5];
    float* out = (float*)d_out;

    const int n = in_sizes[0] / F_IN;
    const int E = in_sizes[1] / 2;
    const int* row = ei;
    const int* col = ei + E;

    const int NW = (n + 127) >> 7;                   // src windows of 128 rows
    const int NC = (n + AGG_CHUNK - 1) / AGG_CHUNK;  // dest chunks
    const int K  = NC * NW;                          // sort bins
    const int nbA = (K + 1023) / 1024;               // scan blocks (<=1024)

    char* p = (char*)d_ws;
    auto alloc = [&](size_t bytes) { void* r = (void*)p; p += (bytes + 255) & ~(size_t)255; return r; };
    int*    cnt     = (int*)alloc((size_t)n * 4);
    int*    keyptr  = (int*)alloc((size_t)(K + 1) * 4);  // hist -> in-place scan
    int*    keycur  = (int*)alloc((size_t)K * 4);
    int*    partial = (int*)alloc(4096);
    float*  dinv    = (float*)alloc((size_t)n * 4);
    int2*   csrd    = (int2*)alloc((size_t)E * 8);
    ushort* Ahi     = (ushort*)alloc((size_t)n * F_IN * 2);
    ushort* Alo     = (ushort*)alloc((size_t)n * F_IN * 2);
    ushort* Hhi     = (ushort*)alloc((size_t)n * F_HID * 2);
    ushort* Hlo     = (ushort*)alloc((size_t)n * F_HID * 2);
    ushort* W1Thi   = (ushort*)alloc((size_t)F_HID * F_IN * 2);
    ushort* W1Tlo   = (ushort*)alloc((size_t)F_HID * F_IN * 2);
    ushort* W2Thi   = (ushort*)alloc((size_t)F_OUT * F_HID * 2);
    ushort* W2Tlo   = (ushort*)alloc((size_t)F_OUT * F_HID * 2);
    float*  bufY    = (float*)Ahi;   // gemm2 out [n][256]; aliases Ahi+Alo (dead by then)

    int nb_n = (n + 255) / 256;
    int nb_e = (E + 255) / 256;

    // zero cnt + keyptr + keycur in one memset (adjacent carve-outs)
    hipMemsetAsync(cnt, 0, (size_t)((char*)partial - (char*)cnt), stream);

    // degree + dinv
    hist_kernel<<<nb_e, 256, 0, stream>>>(col, cnt, E);
    dinv_kernel<<<nb_n, 256, 0, stream>>>(cnt, dinv, n);

    // (chunk, src-window) counting sort of edges
    keyhist_kernel<<<nb_e, 256, 0, stream>>>(row, col, keyptr, E, NW);
    scanA_kernel<<<nbA, 1024, 0, stream>>>(keyptr, partial, K);
    scanB_kernel<<<1, 1024, 0, stream>>>(partial, nbA);
    scanC_kernel<<<nbA, 1024, 0, stream>>>(keyptr, partial, K, E);
    fillkey_kernel<<<nb_e, 256, 0, stream>>>(row, col, keyptr, keycur, dinv, csrd, E, NW);

    // weight transpose+split
    {
        dim3 g1(F_IN / 32, F_HID / 32);
        wsplit_kernel<<<g1, 256, 0, stream>>>(W1, W1Thi, W1Tlo, F_IN, F_HID);
        dim3 g2(F_HID / 32, (F_OUT + 31) / 32);
        wsplit_kernel<<<g2, 256, 0, stream>>>(W2, W2Thi, W2Tlo, F_HID, F_OUT);
    }

    // L1: aggregate X -> split bf16
    agg_lds<1><<<NC, 512, 0, stream>>>(x, dinv, keyptr, csrd, nullptr,
                                       nullptr, Ahi, Alo, n, NW);
    // GEMM1: (AX) @ W1 + b1, relu -> split bf16 H
    {
        dim3 grid((n + 127) / 128, F_HID / 128);
        gemm_mfma<true><<<grid, 256, 0, stream>>>(Ahi, Alo, W1Thi, W1Tlo, b1, nullptr,
                                                  nullptr, Hhi, Hlo, n, F_HID, F_IN, F_HID);
    }
    // GEMM2: H @ W2, epilogue *dinv -> fp32 Ys (ldc=256)
    {
        dim3 grid((n + 127) / 128, (F_OUT + 127) / 128);
        gemm_mfma<false><<<grid, 256, 0, stream>>>(Hhi, Hlo, W2Thi, W2Tlo, nullptr, dinv,
                                                   bufY, nullptr, nullptr, n, F_OUT, F_HID, 256);
    }
    // L2: aggregate Ys (prescaled) + b2, relu -> out
    agg_lds<2><<<NC, 512, 0, stream>>>(bufY, dinv, keyptr, csrd, b2,
                                       out, nullptr, nullptr, n, NW);
}